// Round 12
// baseline (519.545 us; speedup 1.0000x reference)
//
#include <hip/hip_runtime.h>
#include <cstdint>
#include <cstddef>

// ---------------------------------------------------------------------------
// CCA-SSG forward: 2-layer GraphConv (norm='both') x 2 graphs + column z-score
// Round 16: fold scan_block_sums into hist_reduce. Each hist_reduce block's
// int4 degree quads align with scan chunks (1024 nodes = 256 words); a
// segmented LDS reduce (<=3 segments/block at array straddles) + one
// atomicAdd per segment produces spart directly. spart zeroed by hist_kernel
// block 0 (prior dispatch). 8 -> 7 dispatches. Integer sums bit-identical.
// Everything else = R15 (best known 500.5us).
// ---------------------------------------------------------------------------

#define SCAN_CHUNK 1024
#define NSLICES 64          // edge slices per array; 4*64 = 256 blocks = 1/CU
#define HWORDS 25000        // 100000 byte counters = 25000 words = 97.7 KB LDS
#define CSRB 2048           // csr blocks appended to the fused gemm grid

typedef __attribute__((ext_vector_type(8))) short bf16x8;
typedef __attribute__((ext_vector_type(4))) float f32x4;

__device__ __forceinline__ unsigned short f2bf(float f) {
    unsigned int u = __float_as_uint(f);
    unsigned int r = (u + 0x7FFFu + ((u >> 16) & 1u)) >> 16;   // RNE
    return (unsigned short)r;
}
__device__ __forceinline__ float bflo(unsigned int u) { return __uint_as_float(u << 16); }
__device__ __forceinline__ float bfhi(unsigned int u) { return __uint_as_float(u & 0xffff0000u); }

// ---- byte-binned degree histogram: no global atomics ----------------------
// block 0 also zeroes spart (consumed by hist_reduce next dispatch).
__global__ __launch_bounds__(1024) void hist_kernel(
    const int* __restrict__ src1, const int* __restrict__ dst1,
    const int* __restrict__ src2, const int* __restrict__ dst2,
    unsigned int* __restrict__ part, int* __restrict__ spart, int E)
{
    __shared__ unsigned int h[HWORDS];
    const int bid = blockIdx.x;
    if (bid == 0 && threadIdx.x < 512) spart[threadIdx.x] = 0;
    const int a = bid / NSLICES, s = bid % NSLICES;
    const int* idx = a == 0 ? src1 : a == 1 ? dst1 : a == 2 ? src2 : dst2;

    for (int i = threadIdx.x; i < HWORDS; i += 1024) h[i] = 0u;
    __syncthreads();

    const int lo = (int)((long long)s * E / NSLICES);
    const int hi = (int)((long long)(s + 1) * E / NSLICES);
    for (int i = lo + threadIdx.x; i < hi; i += 1024) {
        unsigned int v = (unsigned int)idx[i];
        atomicAdd(&h[v >> 2], 1u << ((v & 3u) << 3));
    }
    __syncthreads();

    unsigned int* out = part + (size_t)bid * HWORDS;
    for (int i = threadIdx.x; i < HWORDS; i += 1024) out[i] = h[i];
}

// hist_reduce + wswz + chunk-sums fused:
//   blocks [0,hrb): reduce byte histograms -> deg, and accumulate per-chunk
//     deg_in sums into spart (segmented LDS reduce, ~1 atomic per segment)
//   blocks [hrb, hrb+128): swizzle W1|W2 into MFMA B-fragment order.
__global__ __launch_bounds__(256) void hist_reduce(
    const unsigned int* __restrict__ part, int* __restrict__ deg, int M, int hrb,
    const float* __restrict__ Wa, const float* __restrict__ Wb,
    unsigned short* __restrict__ Wz, int* __restrict__ spart)
{
    if (blockIdx.x >= hrb) {
        int i = (blockIdx.x - hrb) * 256 + threadIdx.x;     // 0..32767
        const float* W = (i < 16384) ? Wa : Wb;
        int ii = i & 16383;
        int j = ii & 7, l = (ii >> 3) & 63, s = (ii >> 9) & 3, t = ii >> 11;
        int k = s * 32 + ((l >> 4) * 8) + j;
        int n = t * 16 + (l & 15);
        Wz[i] = f2bf(W[k * 128 + n]);
        return;
    }
    __shared__ int skey[256], sval[256];
    int i = blockIdx.x * blockDim.x + threadIdx.x;       // (a, word)
    int key = -1, ssum = 0;
    if (i < 4 * HWORDS) {
        int a = i / HWORDS, w = i % HWORDS;
        const unsigned int* p = part + (size_t)a * NSLICES * HWORDS + w;
        unsigned int accA = 0u, accB = 0u;
#pragma unroll
        for (int s = 0; s < NSLICES; ++s) {
            unsigned int v = p[(size_t)s * HWORDS];
            accA += v & 0x00FF00FFu;
            accB += (v >> 8) & 0x00FF00FFu;
        }
        int4 r = make_int4((int)(accA & 0xFFFFu), (int)(accB & 0xFFFFu),
                           (int)(accA >> 16),     (int)(accB >> 16));
        *(int4*)(deg + (size_t)a * M + 4 * w) = r;
        if (a & 1) {                          // deg_in arrays (a=1 -> g0, a=3 -> g1)
            key = (a >> 1) * 256 + (w >> 8);  // spart slot: g*256 + chunk(=node/1024)
            ssum = r.x + r.y + r.z + r.w;
        }
    }
    skey[threadIdx.x] = key;
    sval[threadIdx.x] = ssum;
    __syncthreads();
    bool leader = (key >= 0) && (threadIdx.x == 0 || skey[threadIdx.x - 1] != key);
    if (leader) {
        int sum = 0;
        for (int t = threadIdx.x; t < 256 && skey[t] == key; ++t) sum += sval[t];
        atomicAdd(&spart[key], sum);
    }
}

// ---- scan stage (fused): block-offset reduce + chunk scan + write ---------
// also zeroes gsum/gsq (block 0).
__global__ void scan_write(const int* __restrict__ deg, const int* __restrict__ partials,
                           int* rp0, int* rp1, int* cu0, int* cu1,
                           double* gsum, double* gsumsq, int M, int P, int goff)
{
    __shared__ int sd[256];
    const int g = blockIdx.y + goff;
    const int* d = deg + (size_t)(2 * g + 1) * M;
    int* rowptr = g ? rp1 : rp0;
    int* cursor = g ? cu1 : cu0;
    if (blockIdx.x == 0) {
        if (threadIdx.x < 128) gsum[g * 128 + threadIdx.x] = 0.0;
        else gsumsq[g * 128 + threadIdx.x - 128] = 0.0;
    }
    // blockoff = sum of partials[t] for t < blockIdx.x (tree reduce in LDS)
    int v = (threadIdx.x < (unsigned)P && threadIdx.x < blockIdx.x)
            ? partials[g * 256 + threadIdx.x] : 0;
    sd[threadIdx.x] = v;
    __syncthreads();
    for (int off = 128; off > 0; off >>= 1) {
        if (threadIdx.x < off) sd[threadIdx.x] += sd[threadIdx.x + off];
        __syncthreads();
    }
    const int boff = sd[0];
    __syncthreads();

    int base = blockIdx.x * SCAN_CHUNK + threadIdx.x * 4;
    int d0 = 0, d1 = 0, d2 = 0, d3 = 0;
    if (base + 0 < M) d0 = d[base + 0];
    if (base + 1 < M) d1 = d[base + 1];
    if (base + 2 < M) d2 = d[base + 2];
    if (base + 3 < M) d3 = d[base + 3];
    int tot = d0 + d1 + d2 + d3;
    sd[threadIdx.x] = tot;
    __syncthreads();
    for (int off = 1; off < 256; off <<= 1) {
        int t = threadIdx.x >= off ? sd[threadIdx.x - off] : 0;
        __syncthreads();
        sd[threadIdx.x] += t;
        __syncthreads();
    }
    int texcl = sd[threadIdx.x] - tot + boff;
    int p0 = texcl + d0, p1 = p0 + d1, p2 = p1 + d2, p3 = p2 + d3;
    if (base + 0 < M) { rowptr[base + 1] = p0; cursor[base + 0] = texcl; }
    if (base + 1 < M) { rowptr[base + 2] = p1; cursor[base + 1] = p0; }
    if (base + 2 < M) { rowptr[base + 3] = p2; cursor[base + 2] = p1; }
    if (base + 3 < M) { rowptr[base + 4] = p3; cursor[base + 3] = p2; }
    if (blockIdx.x == 0 && threadIdx.x == 0) rowptr[0] = 0;
}

// ---- fused layer-1 GEMM (blocks [0,nbg)) + csr_fill (blocks [nbg,...)) ----
__global__ __launch_bounds__(256) void gemm_csr(
    const float* X0, const float* X1, const unsigned short* __restrict__ Wz,
    const int* __restrict__ deg, unsigned short* Y0, unsigned short* Y1,
    const int* s0, const int* s1, const int* d0, const int* d1,
    int* cu0, int* cu1, int* co0, int* co1,
    int E, int M, int nbg, int goff)
{
    __shared__ __align__(16) unsigned short Abf[64 * 136];
    const int g = blockIdx.y + goff;
    const int tid = threadIdx.x;

    if (blockIdx.x >= nbg) {
        // ---------------- csr_fill path ----------------
        const int bx = blockIdx.x - nbg;
        const int* src = g ? s1 : s0;
        const int* dst = g ? d1 : d0;
        int* cursor = g ? cu1 : cu0;
        int* colidx = g ? co1 : co0;

        const int csrB = gridDim.x - nbg;
        const int grp = bx & 7;
        const unsigned int nlo = (unsigned int)((long long)grp * M / 8);
        const unsigned int nspan = (unsigned int)((long long)(grp + 1) * M / 8) - nlo;
        const int nb = csrB >> 3;
        const int bi = bx >> 3;
        const int stride = nb * 256;

        for (int e = bi * 256 + tid; e < E; e += stride) {
            int d = dst[e];
            int sv = src[e];
            if ((unsigned int)(d - nlo) < nspan) {
                int pos = atomicAdd(&cursor[d], 1);
                colidx[pos] = sv;
            }
        }
        return;
    }

    // ---------------- mfma_gemm path ----------------
    const float* X = g ? X1 : X0;
    const int* deg_out = deg + (size_t)2 * g * M;
    unsigned short* Yh = g ? Y1 : Y0;
    const int row0 = blockIdx.x * 64;

#pragma unroll
    for (int i = 0; i < 8; ++i) {
        int idx = tid + i * 256;
        int r = idx >> 5, c4 = idx & 31;
        int gr = row0 + r;
        float4 v = make_float4(0.f, 0.f, 0.f, 0.f);
        if (gr < M) {
            v = ((const float4*)X)[(size_t)gr * 32 + c4];
            float so = rsqrtf(fmaxf((float)deg_out[gr], 1.f));
            v.x *= so; v.y *= so; v.z *= so; v.w *= so;
        }
        unsigned int lo = (unsigned int)f2bf(v.x) | ((unsigned int)f2bf(v.y) << 16);
        unsigned int hi = (unsigned int)f2bf(v.z) | ((unsigned int)f2bf(v.w) << 16);
        *(uint2*)(Abf + r * 136 + c4 * 4) = make_uint2(lo, hi);
    }
    __syncthreads();

    const int w = tid >> 6, lane = tid & 63;
    const int m = lane & 15, quad = lane >> 4;

    bf16x8 a[4];
#pragma unroll
    for (int s = 0; s < 4; ++s)
        a[s] = *(const bf16x8*)(Abf + (w * 16 + m) * 136 + s * 32 + quad * 8);

#pragma unroll
    for (int t = 0; t < 8; ++t) {
        f32x4 acc = {0.f, 0.f, 0.f, 0.f};
#pragma unroll
        for (int s = 0; s < 4; ++s) {
            bf16x8 b = *(const bf16x8*)(Wz + (((t * 4 + s) * 64 + lane) << 3));
            acc = __builtin_amdgcn_mfma_f32_16x16x32_bf16(a[s], b, acc, 0, 0, 0);
        }
        int gr  = row0 + w * 16 + quad * 4;
        int col = t * 16 + m;
#pragma unroll
        for (int r = 0; r < 4; ++r) {
            if (gr + r < M) Yh[(size_t)(gr + r) * 128 + col] = f2bf(acc[r]);
        }
    }
}

// XCD<->graph tile mapping (merged mode): XCDs 0-3 own graph 0, XCDs 4-7
// own graph 1; tiles striped mod 4 within the group.
__device__ __forceinline__ void xcd_tile(int nb, int xcdmap, int goff,
                                         int& g, int& tile)
{
    if (xcdmap) {
        int bid = blockIdx.x;
        int grp = bid & 7;
        g = grp >> 2;
        tile = (bid >> 3) * 4 + (grp & 3);
    } else {
        g = goff;
        tile = blockIdx.x;
    }
}

// 16-lane/node gather: each lane owns 8 consecutive bf16 cols (one uint4).
#define G16_ACC(v)                                                              \
    a0 += bflo(v.x); a1 += bfhi(v.x); a2 += bflo(v.y); a3 += bfhi(v.y);         \
    a4 += bflo(v.z); a5 += bfhi(v.z); a6 += bflo(v.w); a7 += bfhi(v.w);

#define GATHER_ROW16                                                            \
    {                                                                           \
        for (; e + 8 <= end; e += 8) {                                          \
            int c0 = colidx[e+0], c1 = colidx[e+1], c2 = colidx[e+2], c3 = colidx[e+3]; \
            int c4_ = colidx[e+4], c5 = colidx[e+5], c6 = colidx[e+6], c7 = colidx[e+7]; \
            uint4 v0 = Yv[(size_t)c0 * 16 + lane16];                            \
            uint4 v1 = Yv[(size_t)c1 * 16 + lane16];                            \
            uint4 v2 = Yv[(size_t)c2 * 16 + lane16];                            \
            uint4 v3 = Yv[(size_t)c3 * 16 + lane16];                            \
            uint4 v4 = Yv[(size_t)c4_ * 16 + lane16];                           \
            uint4 v5 = Yv[(size_t)c5 * 16 + lane16];                            \
            uint4 v6 = Yv[(size_t)c6 * 16 + lane16];                            \
            uint4 v7 = Yv[(size_t)c7 * 16 + lane16];                            \
            G16_ACC(v0) G16_ACC(v1) G16_ACC(v2) G16_ACC(v3)                     \
            G16_ACC(v4) G16_ACC(v5) G16_ACC(v6) G16_ACC(v7)                     \
        }                                                                       \
        if (e + 4 <= end) {                                                     \
            int c0 = colidx[e+0], c1 = colidx[e+1], c2 = colidx[e+2], c3 = colidx[e+3]; \
            uint4 v0 = Yv[(size_t)c0 * 16 + lane16];                            \
            uint4 v1 = Yv[(size_t)c1 * 16 + lane16];                            \
            uint4 v2 = Yv[(size_t)c2 * 16 + lane16];                            \
            uint4 v3 = Yv[(size_t)c3 * 16 + lane16];                            \
            G16_ACC(v0) G16_ACC(v1) G16_ACC(v2) G16_ACC(v3)                     \
            e += 4;                                                             \
        }                                                                       \
        for (; e < end; ++e) {                                                  \
            int c = colidx[e];                                                  \
            uint4 v = Yv[(size_t)c * 16 + lane16];                              \
            G16_ACC(v)                                                          \
        }                                                                       \
    }

// ---- fused gather(L1) + transform + GEMM(W2): Yh2 = f(A Yh) @ W2 ----------
__global__ __launch_bounds__(256) void spmm_gemm(
    const uint4* Y0, const uint4* Y1, const int* rp0, const int* rp1,
    const int* ci0, const int* ci1, const unsigned short* __restrict__ Wz,
    const int* __restrict__ deg, const float* __restrict__ bias,
    unsigned short* O0, unsigned short* O1, int M, int nb, int xcdmap, int goff)
{
    __shared__ __align__(16) unsigned short Abf[64 * 136];
    int g, tile;
    xcd_tile(nb, xcdmap, goff, g, tile);
    if (tile >= nb) return;
    const uint4* Yv = g ? Y1 : Y0;
    const int* rowptr = g ? rp1 : rp0;
    const int* colidx = g ? ci1 : ci0;
    const int* deg_out = deg + (size_t)2 * g * M;
    const int* deg_in  = deg_out + M;
    unsigned short* Yh2 = g ? O1 : O0;

    const int tid  = threadIdx.x;
    const int row0 = tile * 64;
    const int lane16 = tid & 15;
    const int ng = tid >> 4;                 // node group 0..15
    const float4 bv0 = ((const float4*)bias)[lane16 * 2];
    const float4 bv1 = ((const float4*)bias)[lane16 * 2 + 1];

#pragma unroll 1
    for (int p = 0; p < 4; ++p) {
        const int r = p * 16 + ng;           // row in tile 0..63
        const int node = row0 + r;
        float a0=0.f,a1=0.f,a2=0.f,a3=0.f,a4=0.f,a5=0.f,a6=0.f,a7=0.f;
        if (node < M) {
            int e = rowptr[node], end = rowptr[node + 1];
            GATHER_ROW16
            float si = rsqrtf(fmaxf((float)deg_in[node], 1.f));
            float so = rsqrtf(fmaxf((float)deg_out[node], 1.f));
            a0 = fmaxf(a0 * si + bv0.x, 0.f) * so;
            a1 = fmaxf(a1 * si + bv0.y, 0.f) * so;
            a2 = fmaxf(a2 * si + bv0.z, 0.f) * so;
            a3 = fmaxf(a3 * si + bv0.w, 0.f) * so;
            a4 = fmaxf(a4 * si + bv1.x, 0.f) * so;
            a5 = fmaxf(a5 * si + bv1.y, 0.f) * so;
            a6 = fmaxf(a6 * si + bv1.z, 0.f) * so;
            a7 = fmaxf(a7 * si + bv1.w, 0.f) * so;
        }
        uint4 wv;
        wv.x = (unsigned int)f2bf(a0) | ((unsigned int)f2bf(a1) << 16);
        wv.y = (unsigned int)f2bf(a2) | ((unsigned int)f2bf(a3) << 16);
        wv.z = (unsigned int)f2bf(a4) | ((unsigned int)f2bf(a5) << 16);
        wv.w = (unsigned int)f2bf(a6) | ((unsigned int)f2bf(a7) << 16);
        *(uint4*)(Abf + r * 136 + lane16 * 8) = wv;
    }
    __syncthreads();

    const int w = tid >> 6, lane = tid & 63;
    const int m = lane & 15, quad = lane >> 4;

    bf16x8 a[4];
#pragma unroll
    for (int s = 0; s < 4; ++s)
        a[s] = *(const bf16x8*)(Abf + (w * 16 + m) * 136 + s * 32 + quad * 8);

#pragma unroll
    for (int t = 0; t < 8; ++t) {
        f32x4 acc = {0.f, 0.f, 0.f, 0.f};
#pragma unroll
        for (int s = 0; s < 4; ++s) {
            bf16x8 b = *(const bf16x8*)(Wz + (((t * 4 + s) * 64 + lane) << 3));
            acc = __builtin_amdgcn_mfma_f32_16x16x32_bf16(a[s], b, acc, 0, 0, 0);
        }
        int gr  = row0 + w * 16 + quad * 4;
        int col = t * 16 + m;
#pragma unroll
        for (int r = 0; r < 4; ++r) {
            if (gr + r < M) Yh2[(size_t)(gr + r) * 128 + col] = f2bf(acc[r]);
        }
    }
}

// ---- fused gather(L2) + finalize + column stats: Z = A Yh2 * si + b2 ------
__global__ __launch_bounds__(256) void spmm_stats(
    const uint4* Y0, const uint4* Y1, const int* rp0, const int* rp1,
    const int* ci0, const int* ci1, const int* __restrict__ deg,
    const float* __restrict__ bias, float* __restrict__ Z,
    double* __restrict__ gsum, double* __restrict__ gsumsq,
    int M, int nb, int xcdmap, int goff)
{
    __shared__ float lsum[16][128], lsq[16][128];
    int g, tile;
    xcd_tile(nb, xcdmap, goff, g, tile);
    if (tile >= nb) return;
    const uint4* Yv = g ? Y1 : Y0;
    const int* rowptr = g ? rp1 : rp0;
    const int* colidx = g ? ci1 : ci0;
    const int* deg_in = deg + (size_t)(2 * g + 1) * M;
    float* Zg = Z + (size_t)g * M * 128;
    double* gs = gsum + g * 128;
    double* gq = gsumsq + g * 128;

    const int tid  = threadIdx.x;
    const int row0 = tile * 64;
    const int lane16 = tid & 15;
    const int ng = tid >> 4;
    const float4 bv0 = ((const float4*)bias)[lane16 * 2];
    const float4 bv1 = ((const float4*)bias)[lane16 * 2 + 1];

    float s0=0.f,s1=0.f,s2=0.f,s3=0.f,s4=0.f,s5=0.f,s6=0.f,s7=0.f;
    float q0=0.f,q1=0.f,q2=0.f,q3=0.f,q4=0.f,q5=0.f,q6=0.f,q7=0.f;

#pragma unroll 1
    for (int p = 0; p < 4; ++p) {
        const int node = row0 + p * 16 + ng;
        if (node >= M) continue;
        float a0=0.f,a1=0.f,a2=0.f,a3=0.f,a4=0.f,a5=0.f,a6=0.f,a7=0.f;
        int e = rowptr[node], end = rowptr[node + 1];
        GATHER_ROW16
        float si = rsqrtf(fmaxf((float)deg_in[node], 1.f));
        float h0 = a0 * si + bv0.x, h1 = a1 * si + bv0.y;
        float h2 = a2 * si + bv0.z, h3 = a3 * si + bv0.w;
        float h4 = a4 * si + bv1.x, h5 = a5 * si + bv1.y;
        float h6 = a6 * si + bv1.z, h7 = a7 * si + bv1.w;
        ((float4*)Zg)[(size_t)node * 32 + lane16 * 2]     = make_float4(h0, h1, h2, h3);
        ((float4*)Zg)[(size_t)node * 32 + lane16 * 2 + 1] = make_float4(h4, h5, h6, h7);
        s0 += h0; s1 += h1; s2 += h2; s3 += h3;
        s4 += h4; s5 += h5; s6 += h6; s7 += h7;
        q0 += h0*h0; q1 += h1*h1; q2 += h2*h2; q3 += h3*h3;
        q4 += h4*h4; q5 += h5*h5; q6 += h6*h6; q7 += h7*h7;
    }

    const int cb = lane16 * 8;
    lsum[ng][cb+0]=s0; lsum[ng][cb+1]=s1; lsum[ng][cb+2]=s2; lsum[ng][cb+3]=s3;
    lsum[ng][cb+4]=s4; lsum[ng][cb+5]=s5; lsum[ng][cb+6]=s6; lsum[ng][cb+7]=s7;
    lsq[ng][cb+0]=q0; lsq[ng][cb+1]=q1; lsq[ng][cb+2]=q2; lsq[ng][cb+3]=q3;
    lsq[ng][cb+4]=q4; lsq[ng][cb+5]=q5; lsq[ng][cb+6]=q6; lsq[ng][cb+7]=q7;
    __syncthreads();

    if (tid < 128) {
        float s = 0.f;
#pragma unroll
        for (int g2 = 0; g2 < 16; ++g2) s += lsum[g2][tid];
        atomicAdd(&gs[tid], (double)s);
    } else {
        int c = tid - 128;
        float q = 0.f;
#pragma unroll
        for (int g2 = 0; g2 < 16; ++g2) q += lsq[g2][c];
        atomicAdd(&gq[c], (double)q);
    }
}

// ---- z-score; mean/istd computed per-thread in FLOAT from gsum/gsq --------
__global__ __launch_bounds__(256) void normalize_kernel(
    float* __restrict__ Z, const double* __restrict__ gsum,
    const double* __restrict__ gsumsq, float invM, float invM1,
    int n4_per_g, int n4tot)
{
    int i = blockIdx.x * blockDim.x + threadIdx.x;
    if (i >= n4tot) return;
    int gb = (i >= n4_per_g) ? 128 : 0;
    int c4 = gb + ((i & 31) << 2);
    float4 v = ((float4*)Z)[i];
    float r[4] = {v.x, v.y, v.z, v.w};
#pragma unroll
    for (int j = 0; j < 4; ++j) {
        float sj  = (float)gsum[c4 + j];
        float mu  = sj * invM;
        float var = ((float)gsumsq[c4 + j] - sj * mu) * invM1;
        float is  = 1.0f / sqrtf(var);
        r[j] = (r[j] - mu) * is;
    }
    ((float4*)Z)[i] = make_float4(r[0], r[1], r[2], r[3]);
}

// ---------------------------------------------------------------------------
extern "C" void kernel_launch(void* const* d_in, const int* in_sizes, int n_in,
                              void* d_out, int out_size, void* d_ws, size_t ws_size,
                              hipStream_t stream)
{
    const float* feat1 = (const float*)d_in[0];
    const float* feat2 = (const float*)d_in[1];
    const float* W1    = (const float*)d_in[2];
    const float* b1    = (const float*)d_in[3];
    const float* W2    = (const float*)d_in[4];
    const float* b2    = (const float*)d_in[5];
    const int*   src1  = (const int*)d_in[6];
    const int*   dst1  = (const int*)d_in[7];
    const int*   src2  = (const int*)d_in[8];
    const int*   dst2  = (const int*)d_in[9];
    float* out = (float*)d_out;

    const int M = in_sizes[0] / 128;   // 100000
    const int E = in_sizes[6];         // 800000

    // ---- bump allocator over workspace ----
    char* p0 = (char*)d_ws;
    char* p = p0;
    auto alloc = [&](size_t b) -> char* {
        char* r = p; p += (b + 255) & ~(size_t)255; return r;
    };

    double* gsum = (double*)alloc(256 * 8);
    double* gsq  = (double*)alloc(256 * 8);
    unsigned short* Wz = (unsigned short*)alloc(32768 * 2);
    int* deg = (int*)alloc((size_t)4 * M * 4);
    int* spart = (int*)alloc(512 * 4);

    const size_t bytesRP = (size_t)(M + 1) * 4;
    const size_t bytesCU = (size_t)M * 4;
    const size_t bytesCI = (size_t)E * 4;
    const size_t bytesYh = (size_t)M * 128 * 2;            // 25.6 MB
    const size_t bytesHP = (size_t)4 * NSLICES * HWORDS * 4; // 25.6 MB

    // merged layout needs ~112 MB; check against ws_size, else fallback.
    size_t fixed = (size_t)(p - p0);
    size_t need_merged = fixed + 2 * ((bytesRP + 255 & ~(size_t)255) +
                                      (bytesCU + 255 & ~(size_t)255) +
                                      (bytesCI + 255 & ~(size_t)255) +
                                      2 * ((bytesYh + 255 & ~(size_t)255)));
    const bool merged = ws_size >= need_merged + 4096;

    int *rpA, *rpB, *cuA, *cuB, *ciA, *ciB;
    unsigned short *YhA0, *YhA1, *YhB0, *YhB1;
    unsigned int* hpart;

    if (merged) {
        rpA = (int*)alloc(bytesRP);  rpB = (int*)alloc(bytesRP);
        cuA = (int*)alloc(bytesCU);  cuB = (int*)alloc(bytesCU);
        ciA = (int*)alloc(bytesCI);  ciB = (int*)alloc(bytesCI);
        YhA0 = (unsigned short*)alloc(bytesYh);
        YhA1 = (unsigned short*)alloc(bytesYh);
        YhB0 = (unsigned short*)alloc(bytesYh);
        YhB1 = (unsigned short*)alloc(bytesYh);
        hpart = (unsigned int*)YhA0;   // hist consumed before YhA written
    } else {
        // fallback: single-graph buffers, per-graph sequencing (Round-4 style)
        rpA = (int*)alloc(bytesRP);  rpB = rpA;
        cuA = (int*)alloc(bytesCU);  cuB = cuA;
        ciA = (int*)alloc(bytesCI);  ciB = ciA;
        YhA0 = (unsigned short*)alloc(bytesYh);  YhA1 = YhA0;
        char* scratch = alloc(bytesHP + bytesYh);   // hpart | Yh2
        hpart = (unsigned int*)scratch;
        YhB0 = (unsigned short*)(scratch + bytesHP); YhB1 = YhB0;
    }

    unsigned short* Wz1 = Wz;
    unsigned short* Wz2 = Wz + 16384;

    const int BLK = 256;
    const int gemm_blocks = (M + 63) / 64;                 // 1563
    const int P = (M + SCAN_CHUNK - 1) / SCAN_CHUNK;
    const int NG = merged ? 2 : 1;
    const int hrb = (4 * HWORDS + BLK - 1) / BLK;          // 391
    const float invM  = 1.0f / (float)M;
    const float invM1 = 1.0f / (float)(M - 1);

    // degrees (no global atomics); wswz + chunk-sums fused as hist_reduce
    hist_kernel<<<4 * NSLICES, 1024, 0, stream>>>(src1, dst1, src2, dst2,
                                                  hpart, spart, E);
    hist_reduce<<<hrb + 128, BLK, 0, stream>>>(hpart, deg, M, hrb, W1, W2, Wz, spart);

    for (int g0 = 0; g0 < 2; g0 += NG) {
        dim3 gP(P, NG), gGC(gemm_blocks + CSRB, NG);
        // spmm launch geometry: merged -> 1D XCD-mapped; fallback -> 1D plain
        int spmm_blocks = merged ? 8 * ((2 * gemm_blocks + 7) / 8) : gemm_blocks;
        int xcdmap = merged ? 1 : 0;

        // ---- build CSR prefix (chunk-sums precomputed; + zero gsum/gsq) ----
        scan_write<<<gP, BLK, 0, stream>>>(deg, spart, rpA, rpB, cuA, cuB,
                                           gsum, gsq, M, P, g0);

        // ---- fused layer-1 GEMM + csr_fill (one dispatch, gemm first) ----
        gemm_csr<<<gGC, BLK, 0, stream>>>(
            feat1, feat2, Wz1, deg, YhA0, YhA1,
            src1, src2, dst1, dst2, cuA, cuB, ciA, ciB, E, M, gemm_blocks, g0);

        // ---- fused gather(L1) + transform + GEMM(W2) ----
        spmm_gemm<<<spmm_blocks, BLK, 0, stream>>>(
            (const uint4*)YhA0, (const uint4*)YhA1, rpA, rpB, ciA, ciB,
            Wz2, deg, b1, YhB0, YhB1, M, gemm_blocks, xcdmap, g0);

        // ---- fused gather(L2) + finalize + stats ----
        spmm_stats<<<spmm_blocks, BLK, 0, stream>>>(
            (const uint4*)YhB0, (const uint4*)YhB1, rpA, rpB, ciA, ciB,
            deg, b2, out, gsum, gsq, M, gemm_blocks, xcdmap, g0);

        // ---- z-score (mean/istd folded, float math) ----
        int n4g = M * 32, n4tot = NG * n4g;
        normalize_kernel<<<(n4tot + BLK - 1) / BLK, BLK, 0, stream>>>(
            out + (size_t)g0 * M * 128, gsum + g0 * 128, gsq + g0 * 128,
            invM, invM1, n4g, n4tot);
    }
}

// Round 13
// 500.162 us; speedup vs baseline: 1.0388x; 1.0388x over previous
//
#include <hip/hip_runtime.h>
#include <cstdint>
#include <cstddef>

// ---------------------------------------------------------------------------
// CCA-SSG forward: 2-layer GraphConv (norm='both') x 2 graphs + column z-score
// Round 17: REVERT to R15 exactly (best measured 500.5us). R16's
// scan-fold-into-hist_reduce regressed (serial segmented-reduce leader walk
// on the critical path + L2 perturbation ahead of gemm_csr): 519.5us.
// R15 = R13 fused gemm_csr (gemm-first) + scan_partials folded into
// scan_write + meanstd folded into normalize in FLOAT.
// ---------------------------------------------------------------------------

#define SCAN_CHUNK 1024
#define NSLICES 64          // edge slices per array; 4*64 = 256 blocks = 1/CU
#define HWORDS 25000        // 100000 byte counters = 25000 words = 97.7 KB LDS
#define CSRB 2048           // csr blocks appended to the fused gemm grid

typedef __attribute__((ext_vector_type(8))) short bf16x8;
typedef __attribute__((ext_vector_type(4))) float f32x4;

__device__ __forceinline__ unsigned short f2bf(float f) {
    unsigned int u = __float_as_uint(f);
    unsigned int r = (u + 0x7FFFu + ((u >> 16) & 1u)) >> 16;   // RNE
    return (unsigned short)r;
}
__device__ __forceinline__ float bflo(unsigned int u) { return __uint_as_float(u << 16); }
__device__ __forceinline__ float bfhi(unsigned int u) { return __uint_as_float(u & 0xffff0000u); }

// ---- byte-binned degree histogram: no global atomics ----------------------
__global__ __launch_bounds__(1024) void hist_kernel(
    const int* __restrict__ src1, const int* __restrict__ dst1,
    const int* __restrict__ src2, const int* __restrict__ dst2,
    unsigned int* __restrict__ part, int E)
{
    __shared__ unsigned int h[HWORDS];
    const int bid = blockIdx.x;
    const int a = bid / NSLICES, s = bid % NSLICES;
    const int* idx = a == 0 ? src1 : a == 1 ? dst1 : a == 2 ? src2 : dst2;

    for (int i = threadIdx.x; i < HWORDS; i += 1024) h[i] = 0u;
    __syncthreads();

    const int lo = (int)((long long)s * E / NSLICES);
    const int hi = (int)((long long)(s + 1) * E / NSLICES);
    for (int i = lo + threadIdx.x; i < hi; i += 1024) {
        unsigned int v = (unsigned int)idx[i];
        atomicAdd(&h[v >> 2], 1u << ((v & 3u) << 3));
    }
    __syncthreads();

    unsigned int* out = part + (size_t)bid * HWORDS;
    for (int i = threadIdx.x; i < HWORDS; i += 1024) out[i] = h[i];
}

// hist_reduce + wswz fused: blocks [0,hrb) reduce byte histograms; blocks
// [hrb, hrb+128) swizzle W1|W2 into MFMA B-fragment order.
__global__ __launch_bounds__(256) void hist_reduce(
    const unsigned int* __restrict__ part, int* __restrict__ deg, int M, int hrb,
    const float* __restrict__ Wa, const float* __restrict__ Wb,
    unsigned short* __restrict__ Wz)
{
    if (blockIdx.x >= hrb) {
        int i = (blockIdx.x - hrb) * 256 + threadIdx.x;     // 0..32767
        const float* W = (i < 16384) ? Wa : Wb;
        int ii = i & 16383;
        int j = ii & 7, l = (ii >> 3) & 63, s = (ii >> 9) & 3, t = ii >> 11;
        int k = s * 32 + ((l >> 4) * 8) + j;
        int n = t * 16 + (l & 15);
        Wz[i] = f2bf(W[k * 128 + n]);
        return;
    }
    int i = blockIdx.x * blockDim.x + threadIdx.x;       // (a, word)
    if (i >= 4 * HWORDS) return;
    int a = i / HWORDS, w = i % HWORDS;
    const unsigned int* p = part + (size_t)a * NSLICES * HWORDS + w;
    unsigned int accA = 0u, accB = 0u;
#pragma unroll
    for (int s = 0; s < NSLICES; ++s) {
        unsigned int v = p[(size_t)s * HWORDS];
        accA += v & 0x00FF00FFu;
        accB += (v >> 8) & 0x00FF00FFu;
    }
    int4 r = make_int4((int)(accA & 0xFFFFu), (int)(accB & 0xFFFFu),
                       (int)(accA >> 16),     (int)(accB >> 16));
    *(int4*)(deg + (size_t)a * M + 4 * w) = r;
}

// ---- scan stage 1: per-chunk sums -----------------------------------------
__global__ void scan_block_sums(const int* __restrict__ deg, int* __restrict__ partials,
                                int M, int goff)
{
    __shared__ int sd[256];
    const int g = blockIdx.y + goff;
    const int* d = deg + (size_t)(2 * g + 1) * M;
    int base = blockIdx.x * SCAN_CHUNK + threadIdx.x * 4;
    int s = 0;
#pragma unroll
    for (int j = 0; j < 4; ++j) { int i = base + j; if (i < M) s += d[i]; }
    sd[threadIdx.x] = s;
    __syncthreads();
    for (int off = 128; off > 0; off >>= 1) {
        if (threadIdx.x < off) sd[threadIdx.x] += sd[threadIdx.x + off];
        __syncthreads();
    }
    if (threadIdx.x == 0) partials[g * 256 + blockIdx.x] = sd[0];
}

// ---- scan stage 2 (fused): block-offset reduce + chunk scan + write -------
// also zeroes gsum/gsq (block 0) — drops hipMemsetAsync and scan_partials.
__global__ void scan_write(const int* __restrict__ deg, const int* __restrict__ partials,
                           int* rp0, int* rp1, int* cu0, int* cu1,
                           double* gsum, double* gsumsq, int M, int P, int goff)
{
    __shared__ int sd[256];
    const int g = blockIdx.y + goff;
    const int* d = deg + (size_t)(2 * g + 1) * M;
    int* rowptr = g ? rp1 : rp0;
    int* cursor = g ? cu1 : cu0;
    if (blockIdx.x == 0) {
        if (threadIdx.x < 128) gsum[g * 128 + threadIdx.x] = 0.0;
        else gsumsq[g * 128 + threadIdx.x - 128] = 0.0;
    }
    // blockoff = sum of partials[t] for t < blockIdx.x (tree reduce in LDS)
    int v = (threadIdx.x < (unsigned)P && threadIdx.x < blockIdx.x)
            ? partials[g * 256 + threadIdx.x] : 0;
    sd[threadIdx.x] = v;
    __syncthreads();
    for (int off = 128; off > 0; off >>= 1) {
        if (threadIdx.x < off) sd[threadIdx.x] += sd[threadIdx.x + off];
        __syncthreads();
    }
    const int boff = sd[0];
    __syncthreads();

    int base = blockIdx.x * SCAN_CHUNK + threadIdx.x * 4;
    int d0 = 0, d1 = 0, d2 = 0, d3 = 0;
    if (base + 0 < M) d0 = d[base + 0];
    if (base + 1 < M) d1 = d[base + 1];
    if (base + 2 < M) d2 = d[base + 2];
    if (base + 3 < M) d3 = d[base + 3];
    int tot = d0 + d1 + d2 + d3;
    sd[threadIdx.x] = tot;
    __syncthreads();
    for (int off = 1; off < 256; off <<= 1) {
        int t = threadIdx.x >= off ? sd[threadIdx.x - off] : 0;
        __syncthreads();
        sd[threadIdx.x] += t;
        __syncthreads();
    }
    int texcl = sd[threadIdx.x] - tot + boff;
    int p0 = texcl + d0, p1 = p0 + d1, p2 = p1 + d2, p3 = p2 + d3;
    if (base + 0 < M) { rowptr[base + 1] = p0; cursor[base + 0] = texcl; }
    if (base + 1 < M) { rowptr[base + 2] = p1; cursor[base + 1] = p0; }
    if (base + 2 < M) { rowptr[base + 3] = p2; cursor[base + 2] = p1; }
    if (base + 3 < M) { rowptr[base + 4] = p3; cursor[base + 3] = p2; }
    if (blockIdx.x == 0 && threadIdx.x == 0) rowptr[0] = 0;
}

// ---- fused layer-1 GEMM (blocks [0,nbg)) + csr_fill (blocks [nbg,...)) ----
// R13 ordering (gemm first) — best measured config.
__global__ __launch_bounds__(256) void gemm_csr(
    const float* X0, const float* X1, const unsigned short* __restrict__ Wz,
    const int* __restrict__ deg, unsigned short* Y0, unsigned short* Y1,
    const int* s0, const int* s1, const int* d0, const int* d1,
    int* cu0, int* cu1, int* co0, int* co1,
    int E, int M, int nbg, int goff)
{
    __shared__ __align__(16) unsigned short Abf[64 * 136];
    const int g = blockIdx.y + goff;
    const int tid = threadIdx.x;

    if (blockIdx.x >= nbg) {
        // ---------------- csr_fill path ----------------
        const int bx = blockIdx.x - nbg;
        const int* src = g ? s1 : s0;
        const int* dst = g ? d1 : d0;
        int* cursor = g ? cu1 : cu0;
        int* colidx = g ? co1 : co0;

        const int csrB = gridDim.x - nbg;
        const int grp = bx & 7;
        const unsigned int nlo = (unsigned int)((long long)grp * M / 8);
        const unsigned int nspan = (unsigned int)((long long)(grp + 1) * M / 8) - nlo;
        const int nb = csrB >> 3;
        const int bi = bx >> 3;
        const int stride = nb * 256;

        for (int e = bi * 256 + tid; e < E; e += stride) {
            int d = dst[e];
            int sv = src[e];
            if ((unsigned int)(d - nlo) < nspan) {
                int pos = atomicAdd(&cursor[d], 1);
                colidx[pos] = sv;
            }
        }
        return;
    }

    // ---------------- mfma_gemm path ----------------
    const float* X = g ? X1 : X0;
    const int* deg_out = deg + (size_t)2 * g * M;
    unsigned short* Yh = g ? Y1 : Y0;
    const int row0 = blockIdx.x * 64;

#pragma unroll
    for (int i = 0; i < 8; ++i) {
        int idx = tid + i * 256;
        int r = idx >> 5, c4 = idx & 31;
        int gr = row0 + r;
        float4 v = make_float4(0.f, 0.f, 0.f, 0.f);
        if (gr < M) {
            v = ((const float4*)X)[(size_t)gr * 32 + c4];
            float so = rsqrtf(fmaxf((float)deg_out[gr], 1.f));
            v.x *= so; v.y *= so; v.z *= so; v.w *= so;
        }
        unsigned int lo = (unsigned int)f2bf(v.x) | ((unsigned int)f2bf(v.y) << 16);
        unsigned int hi = (unsigned int)f2bf(v.z) | ((unsigned int)f2bf(v.w) << 16);
        *(uint2*)(Abf + r * 136 + c4 * 4) = make_uint2(lo, hi);
    }
    __syncthreads();

    const int w = tid >> 6, lane = tid & 63;
    const int m = lane & 15, quad = lane >> 4;

    bf16x8 a[4];
#pragma unroll
    for (int s = 0; s < 4; ++s)
        a[s] = *(const bf16x8*)(Abf + (w * 16 + m) * 136 + s * 32 + quad * 8);

#pragma unroll
    for (int t = 0; t < 8; ++t) {
        f32x4 acc = {0.f, 0.f, 0.f, 0.f};
#pragma unroll
        for (int s = 0; s < 4; ++s) {
            bf16x8 b = *(const bf16x8*)(Wz + (((t * 4 + s) * 64 + lane) << 3));
            acc = __builtin_amdgcn_mfma_f32_16x16x32_bf16(a[s], b, acc, 0, 0, 0);
        }
        int gr  = row0 + w * 16 + quad * 4;
        int col = t * 16 + m;
#pragma unroll
        for (int r = 0; r < 4; ++r) {
            if (gr + r < M) Yh[(size_t)(gr + r) * 128 + col] = f2bf(acc[r]);
        }
    }
}

// XCD<->graph tile mapping (merged mode): XCDs 0-3 own graph 0, XCDs 4-7
// own graph 1; tiles striped mod 4 within the group.
__device__ __forceinline__ void xcd_tile(int nb, int xcdmap, int goff,
                                         int& g, int& tile)
{
    if (xcdmap) {
        int bid = blockIdx.x;
        int grp = bid & 7;
        g = grp >> 2;
        tile = (bid >> 3) * 4 + (grp & 3);
    } else {
        g = goff;
        tile = blockIdx.x;
    }
}

// 16-lane/node gather: each lane owns 8 consecutive bf16 cols (one uint4).
#define G16_ACC(v)                                                              \
    a0 += bflo(v.x); a1 += bfhi(v.x); a2 += bflo(v.y); a3 += bfhi(v.y);         \
    a4 += bflo(v.z); a5 += bfhi(v.z); a6 += bflo(v.w); a7 += bfhi(v.w);

#define GATHER_ROW16                                                            \
    {                                                                           \
        for (; e + 8 <= end; e += 8) {                                          \
            int c0 = colidx[e+0], c1 = colidx[e+1], c2 = colidx[e+2], c3 = colidx[e+3]; \
            int c4_ = colidx[e+4], c5 = colidx[e+5], c6 = colidx[e+6], c7 = colidx[e+7]; \
            uint4 v0 = Yv[(size_t)c0 * 16 + lane16];                            \
            uint4 v1 = Yv[(size_t)c1 * 16 + lane16];                            \
            uint4 v2 = Yv[(size_t)c2 * 16 + lane16];                            \
            uint4 v3 = Yv[(size_t)c3 * 16 + lane16];                            \
            uint4 v4 = Yv[(size_t)c4_ * 16 + lane16];                           \
            uint4 v5 = Yv[(size_t)c5 * 16 + lane16];                            \
            uint4 v6 = Yv[(size_t)c6 * 16 + lane16];                            \
            uint4 v7 = Yv[(size_t)c7 * 16 + lane16];                            \
            G16_ACC(v0) G16_ACC(v1) G16_ACC(v2) G16_ACC(v3)                     \
            G16_ACC(v4) G16_ACC(v5) G16_ACC(v6) G16_ACC(v7)                     \
        }                                                                       \
        if (e + 4 <= end) {                                                     \
            int c0 = colidx[e+0], c1 = colidx[e+1], c2 = colidx[e+2], c3 = colidx[e+3]; \
            uint4 v0 = Yv[(size_t)c0 * 16 + lane16];                            \
            uint4 v1 = Yv[(size_t)c1 * 16 + lane16];                            \
            uint4 v2 = Yv[(size_t)c2 * 16 + lane16];                            \
            uint4 v3 = Yv[(size_t)c3 * 16 + lane16];                            \
            G16_ACC(v0) G16_ACC(v1) G16_ACC(v2) G16_ACC(v3)                     \
            e += 4;                                                             \
        }                                                                       \
        for (; e < end; ++e) {                                                  \
            int c = colidx[e];                                                  \
            uint4 v = Yv[(size_t)c * 16 + lane16];                              \
            G16_ACC(v)                                                          \
        }                                                                       \
    }

// ---- fused gather(L1) + transform + GEMM(W2): Yh2 = f(A Yh) @ W2 ----------
__global__ __launch_bounds__(256) void spmm_gemm(
    const uint4* Y0, const uint4* Y1, const int* rp0, const int* rp1,
    const int* ci0, const int* ci1, const unsigned short* __restrict__ Wz,
    const int* __restrict__ deg, const float* __restrict__ bias,
    unsigned short* O0, unsigned short* O1, int M, int nb, int xcdmap, int goff)
{
    __shared__ __align__(16) unsigned short Abf[64 * 136];
    int g, tile;
    xcd_tile(nb, xcdmap, goff, g, tile);
    if (tile >= nb) return;
    const uint4* Yv = g ? Y1 : Y0;
    const int* rowptr = g ? rp1 : rp0;
    const int* colidx = g ? ci1 : ci0;
    const int* deg_out = deg + (size_t)2 * g * M;
    const int* deg_in  = deg_out + M;
    unsigned short* Yh2 = g ? O1 : O0;

    const int tid  = threadIdx.x;
    const int row0 = tile * 64;
    const int lane16 = tid & 15;
    const int ng = tid >> 4;                 // node group 0..15
    const float4 bv0 = ((const float4*)bias)[lane16 * 2];
    const float4 bv1 = ((const float4*)bias)[lane16 * 2 + 1];

#pragma unroll 1
    for (int p = 0; p < 4; ++p) {
        const int r = p * 16 + ng;           // row in tile 0..63
        const int node = row0 + r;
        float a0=0.f,a1=0.f,a2=0.f,a3=0.f,a4=0.f,a5=0.f,a6=0.f,a7=0.f;
        if (node < M) {
            int e = rowptr[node], end = rowptr[node + 1];
            GATHER_ROW16
            float si = rsqrtf(fmaxf((float)deg_in[node], 1.f));
            float so = rsqrtf(fmaxf((float)deg_out[node], 1.f));
            a0 = fmaxf(a0 * si + bv0.x, 0.f) * so;
            a1 = fmaxf(a1 * si + bv0.y, 0.f) * so;
            a2 = fmaxf(a2 * si + bv0.z, 0.f) * so;
            a3 = fmaxf(a3 * si + bv0.w, 0.f) * so;
            a4 = fmaxf(a4 * si + bv1.x, 0.f) * so;
            a5 = fmaxf(a5 * si + bv1.y, 0.f) * so;
            a6 = fmaxf(a6 * si + bv1.z, 0.f) * so;
            a7 = fmaxf(a7 * si + bv1.w, 0.f) * so;
        }
        uint4 wv;
        wv.x = (unsigned int)f2bf(a0) | ((unsigned int)f2bf(a1) << 16);
        wv.y = (unsigned int)f2bf(a2) | ((unsigned int)f2bf(a3) << 16);
        wv.z = (unsigned int)f2bf(a4) | ((unsigned int)f2bf(a5) << 16);
        wv.w = (unsigned int)f2bf(a6) | ((unsigned int)f2bf(a7) << 16);
        *(uint4*)(Abf + r * 136 + lane16 * 8) = wv;
    }
    __syncthreads();

    const int w = tid >> 6, lane = tid & 63;
    const int m = lane & 15, quad = lane >> 4;

    bf16x8 a[4];
#pragma unroll
    for (int s = 0; s < 4; ++s)
        a[s] = *(const bf16x8*)(Abf + (w * 16 + m) * 136 + s * 32 + quad * 8);

#pragma unroll
    for (int t = 0; t < 8; ++t) {
        f32x4 acc = {0.f, 0.f, 0.f, 0.f};
#pragma unroll
        for (int s = 0; s < 4; ++s) {
            bf16x8 b = *(const bf16x8*)(Wz + (((t * 4 + s) * 64 + lane) << 3));
            acc = __builtin_amdgcn_mfma_f32_16x16x32_bf16(a[s], b, acc, 0, 0, 0);
        }
        int gr  = row0 + w * 16 + quad * 4;
        int col = t * 16 + m;
#pragma unroll
        for (int r = 0; r < 4; ++r) {
            if (gr + r < M) Yh2[(size_t)(gr + r) * 128 + col] = f2bf(acc[r]);
        }
    }
}

// ---- fused gather(L2) + finalize + column stats: Z = A Yh2 * si + b2 ------
__global__ __launch_bounds__(256) void spmm_stats(
    const uint4* Y0, const uint4* Y1, const int* rp0, const int* rp1,
    const int* ci0, const int* ci1, const int* __restrict__ deg,
    const float* __restrict__ bias, float* __restrict__ Z,
    double* __restrict__ gsum, double* __restrict__ gsumsq,
    int M, int nb, int xcdmap, int goff)
{
    __shared__ float lsum[16][128], lsq[16][128];
    int g, tile;
    xcd_tile(nb, xcdmap, goff, g, tile);
    if (tile >= nb) return;
    const uint4* Yv = g ? Y1 : Y0;
    const int* rowptr = g ? rp1 : rp0;
    const int* colidx = g ? ci1 : ci0;
    const int* deg_in = deg + (size_t)(2 * g + 1) * M;
    float* Zg = Z + (size_t)g * M * 128;
    double* gs = gsum + g * 128;
    double* gq = gsumsq + g * 128;

    const int tid  = threadIdx.x;
    const int row0 = tile * 64;
    const int lane16 = tid & 15;
    const int ng = tid >> 4;
    const float4 bv0 = ((const float4*)bias)[lane16 * 2];
    const float4 bv1 = ((const float4*)bias)[lane16 * 2 + 1];

    float s0=0.f,s1=0.f,s2=0.f,s3=0.f,s4=0.f,s5=0.f,s6=0.f,s7=0.f;
    float q0=0.f,q1=0.f,q2=0.f,q3=0.f,q4=0.f,q5=0.f,q6=0.f,q7=0.f;

#pragma unroll 1
    for (int p = 0; p < 4; ++p) {
        const int node = row0 + p * 16 + ng;
        if (node >= M) continue;
        float a0=0.f,a1=0.f,a2=0.f,a3=0.f,a4=0.f,a5=0.f,a6=0.f,a7=0.f;
        int e = rowptr[node], end = rowptr[node + 1];
        GATHER_ROW16
        float si = rsqrtf(fmaxf((float)deg_in[node], 1.f));
        float h0 = a0 * si + bv0.x, h1 = a1 * si + bv0.y;
        float h2 = a2 * si + bv0.z, h3 = a3 * si + bv0.w;
        float h4 = a4 * si + bv1.x, h5 = a5 * si + bv1.y;
        float h6 = a6 * si + bv1.z, h7 = a7 * si + bv1.w;
        ((float4*)Zg)[(size_t)node * 32 + lane16 * 2]     = make_float4(h0, h1, h2, h3);
        ((float4*)Zg)[(size_t)node * 32 + lane16 * 2 + 1] = make_float4(h4, h5, h6, h7);
        s0 += h0; s1 += h1; s2 += h2; s3 += h3;
        s4 += h4; s5 += h5; s6 += h6; s7 += h7;
        q0 += h0*h0; q1 += h1*h1; q2 += h2*h2; q3 += h3*h3;
        q4 += h4*h4; q5 += h5*h5; q6 += h6*h6; q7 += h7*h7;
    }

    const int cb = lane16 * 8;
    lsum[ng][cb+0]=s0; lsum[ng][cb+1]=s1; lsum[ng][cb+2]=s2; lsum[ng][cb+3]=s3;
    lsum[ng][cb+4]=s4; lsum[ng][cb+5]=s5; lsum[ng][cb+6]=s6; lsum[ng][cb+7]=s7;
    lsq[ng][cb+0]=q0; lsq[ng][cb+1]=q1; lsq[ng][cb+2]=q2; lsq[ng][cb+3]=q3;
    lsq[ng][cb+4]=q4; lsq[ng][cb+5]=q5; lsq[ng][cb+6]=q6; lsq[ng][cb+7]=q7;
    __syncthreads();

    if (tid < 128) {
        float s = 0.f;
#pragma unroll
        for (int g2 = 0; g2 < 16; ++g2) s += lsum[g2][tid];
        atomicAdd(&gs[tid], (double)s);
    } else {
        int c = tid - 128;
        float q = 0.f;
#pragma unroll
        for (int g2 = 0; g2 < 16; ++g2) q += lsq[g2][c];
        atomicAdd(&gq[c], (double)q);
    }
}

// ---- z-score; mean/istd computed per-thread in FLOAT from gsum/gsq --------
// (float div + sqrtf ~8cyc each; R3's regression was DOUBLE div/sqrt)
__global__ __launch_bounds__(256) void normalize_kernel(
    float* __restrict__ Z, const double* __restrict__ gsum,
    const double* __restrict__ gsumsq, float invM, float invM1,
    int n4_per_g, int n4tot)
{
    int i = blockIdx.x * blockDim.x + threadIdx.x;
    if (i >= n4tot) return;
    int gb = (i >= n4_per_g) ? 128 : 0;
    int c4 = gb + ((i & 31) << 2);
    float4 v = ((float4*)Z)[i];
    float r[4] = {v.x, v.y, v.z, v.w};
#pragma unroll
    for (int j = 0; j < 4; ++j) {
        float sj  = (float)gsum[c4 + j];
        float mu  = sj * invM;
        float var = ((float)gsumsq[c4 + j] - sj * mu) * invM1;
        float is  = 1.0f / sqrtf(var);
        r[j] = (r[j] - mu) * is;
    }
    ((float4*)Z)[i] = make_float4(r[0], r[1], r[2], r[3]);
}

// ---------------------------------------------------------------------------
extern "C" void kernel_launch(void* const* d_in, const int* in_sizes, int n_in,
                              void* d_out, int out_size, void* d_ws, size_t ws_size,
                              hipStream_t stream)
{
    const float* feat1 = (const float*)d_in[0];
    const float* feat2 = (const float*)d_in[1];
    const float* W1    = (const float*)d_in[2];
    const float* b1    = (const float*)d_in[3];
    const float* W2    = (const float*)d_in[4];
    const float* b2    = (const float*)d_in[5];
    const int*   src1  = (const int*)d_in[6];
    const int*   dst1  = (const int*)d_in[7];
    const int*   src2  = (const int*)d_in[8];
    const int*   dst2  = (const int*)d_in[9];
    float* out = (float*)d_out;

    const int M = in_sizes[0] / 128;   // 100000
    const int E = in_sizes[6];         // 800000

    // ---- bump allocator over workspace ----
    char* p0 = (char*)d_ws;
    char* p = p0;
    auto alloc = [&](size_t b) -> char* {
        char* r = p; p += (b + 255) & ~(size_t)255; return r;
    };

    double* gsum = (double*)alloc(256 * 8);
    double* gsq  = (double*)alloc(256 * 8);
    unsigned short* Wz = (unsigned short*)alloc(32768 * 2);
    int* deg = (int*)alloc((size_t)4 * M * 4);
    int* spart = (int*)alloc(512 * 4);

    const size_t bytesRP = (size_t)(M + 1) * 4;
    const size_t bytesCU = (size_t)M * 4;
    const size_t bytesCI = (size_t)E * 4;
    const size_t bytesYh = (size_t)M * 128 * 2;            // 25.6 MB
    const size_t bytesHP = (size_t)4 * NSLICES * HWORDS * 4; // 25.6 MB

    // merged layout needs ~112 MB; check against ws_size, else fallback.
    size_t fixed = (size_t)(p - p0);
    size_t need_merged = fixed + 2 * ((bytesRP + 255 & ~(size_t)255) +
                                      (bytesCU + 255 & ~(size_t)255) +
                                      (bytesCI + 255 & ~(size_t)255) +
                                      2 * ((bytesYh + 255 & ~(size_t)255)));
    const bool merged = ws_size >= need_merged + 4096;

    int *rpA, *rpB, *cuA, *cuB, *ciA, *ciB;
    unsigned short *YhA0, *YhA1, *YhB0, *YhB1;
    unsigned int* hpart;

    if (merged) {
        rpA = (int*)alloc(bytesRP);  rpB = (int*)alloc(bytesRP);
        cuA = (int*)alloc(bytesCU);  cuB = (int*)alloc(bytesCU);
        ciA = (int*)alloc(bytesCI);  ciB = (int*)alloc(bytesCI);
        YhA0 = (unsigned short*)alloc(bytesYh);
        YhA1 = (unsigned short*)alloc(bytesYh);
        YhB0 = (unsigned short*)alloc(bytesYh);
        YhB1 = (unsigned short*)alloc(bytesYh);
        hpart = (unsigned int*)YhA0;   // hist consumed before YhA written
    } else {
        // fallback: single-graph buffers, per-graph sequencing (Round-4 style)
        rpA = (int*)alloc(bytesRP);  rpB = rpA;
        cuA = (int*)alloc(bytesCU);  cuB = cuA;
        ciA = (int*)alloc(bytesCI);  ciB = ciA;
        YhA0 = (unsigned short*)alloc(bytesYh);  YhA1 = YhA0;
        char* scratch = alloc(bytesHP + bytesYh);   // hpart | Yh2
        hpart = (unsigned int*)scratch;
        YhB0 = (unsigned short*)(scratch + bytesHP); YhB1 = YhB0;
    }

    unsigned short* Wz1 = Wz;
    unsigned short* Wz2 = Wz + 16384;

    const int BLK = 256;
    const int gemm_blocks = (M + 63) / 64;                 // 1563
    const int P = (M + SCAN_CHUNK - 1) / SCAN_CHUNK;
    const int NG = merged ? 2 : 1;
    const int hrb = (4 * HWORDS + BLK - 1) / BLK;          // 391
    const float invM  = 1.0f / (float)M;
    const float invM1 = 1.0f / (float)(M - 1);

    // degrees (no global atomics); wswz fused as tail blocks
    hist_kernel<<<4 * NSLICES, 1024, 0, stream>>>(src1, dst1, src2, dst2, hpart, E);
    hist_reduce<<<hrb + 128, BLK, 0, stream>>>(hpart, deg, M, hrb, W1, W2, Wz);

    for (int g0 = 0; g0 < 2; g0 += NG) {
        dim3 gP(P, NG), gGC(gemm_blocks + CSRB, NG);
        // spmm launch geometry: merged -> 1D XCD-mapped; fallback -> 1D plain
        int spmm_blocks = merged ? 8 * ((2 * gemm_blocks + 7) / 8) : gemm_blocks;
        int xcdmap = merged ? 1 : 0;

        // ---- build CSR prefix (scan_partials folded; + zero gsum/gsq) ----
        scan_block_sums<<<gP, BLK, 0, stream>>>(deg, spart, M, g0);
        scan_write<<<gP, BLK, 0, stream>>>(deg, spart, rpA, rpB, cuA, cuB,
                                           gsum, gsq, M, P, g0);

        // ---- fused layer-1 GEMM + csr_fill (one dispatch, gemm first) ----
        gemm_csr<<<gGC, BLK, 0, stream>>>(
            feat1, feat2, Wz1, deg, YhA0, YhA1,
            src1, src2, dst1, dst2, cuA, cuB, ciA, ciB, E, M, gemm_blocks, g0);

        // ---- fused gather(L1) + transform + GEMM(W2) ----
        spmm_gemm<<<spmm_blocks, BLK, 0, stream>>>(
            (const uint4*)YhA0, (const uint4*)YhA1, rpA, rpB, ciA, ciB,
            Wz2, deg, b1, YhB0, YhB1, M, gemm_blocks, xcdmap, g0);

        // ---- fused gather(L2) + finalize + stats ----
        spmm_stats<<<spmm_blocks, BLK, 0, stream>>>(
            (const uint4*)YhB0, (const uint4*)YhB1, rpA, rpB, ciA, ciB,
            deg, b2, out, gsum, gsq, M, gemm_blocks, xcdmap, g0);

        // ---- z-score (mean/istd folded, float math) ----
        int n4g = M * 32, n4tot = NG * n4g;
        normalize_kernel<<<(n4tot + BLK - 1) / BLK, BLK, 0, stream>>>(
            out + (size_t)g0 * M * 128, gsum + g0 * 128, gsq + g0 * 128,
            invM, invM1, n4g, n4tot);
    }
}